// Round 3
// baseline (243.151 us; speedup 1.0000x reference)
//
#include <hip/hip_runtime.h>
#include <hip/hip_bf16.h>

#define NN 4096
#define HID 2048
#define BATCH 64
#define NSEG 32
#define ISEG 128          // 4096/32
#define LOG2E 1.4426950408889634f

__device__ __forceinline__ float rcpf(float v) { return __builtin_amdgcn_rcpf(v); }
__device__ __forceinline__ float exp2f_(float v) { return __builtin_amdgcn_exp2f(v); }

template <int CTRL>
__device__ __forceinline__ float ror_add(float x) {
    int t = __builtin_amdgcn_update_dpp(0, __builtin_bit_cast(int, x), CTRL, 0xF, 0xF, true);
    return x + __builtin_bit_cast(float, t);
}

// ---------------- K0: pack x bits ----------------
__global__ __launch_bounds__(256) void k_pack(const float* __restrict__ x,
                                              unsigned long long* __restrict__ xbits) {
    int gw = blockIdx.x * 4 + (threadIdx.x >> 6);   // global wave id, 0..4095
    int lane = threadIdx.x & 63;
    int b = gw >> 6, w = gw & 63;
    float v = x[(size_t)b * NN + w * 64 + lane];
    unsigned long long m = __ballot(v > 0.5f);
    if (lane == 0) xbits[b * 64 + w] = m;
}

// ---------------- K_wt: transpose W, store uw = 2^(-w*log2e) ----------------
__global__ __launch_bounds__(256) void k_wt(const float* __restrict__ W,
                                            float* __restrict__ Wt) {
    __shared__ float lt[64 * 68];
    const int t = threadIdx.x;
    const int i0 = blockIdx.x * 64, h0 = blockIdx.y * 64;
    const int c4 = (t & 15) * 4, rbase = t >> 4;    // rbase 0..15
    #pragma unroll
    for (int rr = 0; rr < 4; ++rr) {
        int row = rr * 16 + rbase;
        float4 w4 = *(const float4*)&W[(size_t)(h0 + row) * NN + i0 + c4];
        *(float4*)&lt[row * 68 + c4] = w4;
    }
    __syncthreads();
    #pragma unroll
    for (int rr = 0; rr < 4; ++rr) {
        int irow = rr * 16 + rbase;
        float4 o;
        o.x = exp2f_(-LOG2E * lt[(c4 + 0) * 68 + irow]);
        o.y = exp2f_(-LOG2E * lt[(c4 + 1) * 68 + irow]);
        o.z = exp2f_(-LOG2E * lt[(c4 + 2) * 68 + irow]);
        o.w = exp2f_(-LOG2E * lt[(c4 + 3) * 68 + irow]);
        *(float4*)&Wt[(size_t)(i0 + irow) * HID + h0 + c4] = o;
    }
}

// ---------------- K1: per-segment products Cm[seg][b][h] = prod uw ----------------
__global__ __launch_bounds__(256) void k_partial(const float* __restrict__ Wt,
                                                 const unsigned* __restrict__ xb32,
                                                 float* __restrict__ C) {
    const int tid = threadIdx.x, lane = tid & 63, wv = tid >> 6;
    const int hb = blockIdx.x * 256;
    const int ib = blockIdx.y * ISEG;
    const int bb = blockIdx.z * 16 + wv * 4;
    const int hh = hb + 4 * lane;

    float4 acc[4];
    #pragma unroll
    for (int k = 0; k < 4; ++k) acc[k] = make_float4(1.f, 1.f, 1.f, 1.f);

    for (int tq = 0; tq < 4; ++tq) {
        unsigned sx[4];
        #pragma unroll
        for (int k = 0; k < 4; ++k)
            sx[k] = (unsigned)__builtin_amdgcn_readfirstlane(
                (int)xb32[(bb + k) * 128 + (ib >> 5) + tq]);
        #pragma unroll 4
        for (int ii = 0; ii < 32; ++ii) {
            const int ig = ib + tq * 32 + ii;
            float4 w4 = *(const float4*)&Wt[(size_t)ig * HID + hh];
            #pragma unroll
            for (int k = 0; k < 4; ++k) {
                if ((sx[k] >> ii) & 1u) {
                    acc[k].x *= w4.x; acc[k].y *= w4.y;
                    acc[k].z *= w4.z; acc[k].w *= w4.w;
                }
            }
        }
    }
    #pragma unroll
    for (int k = 0; k < 4; ++k)
        *(float4*)&C[(size_t)blockIdx.y * (BATCH * HID) + (size_t)(bb + k) * HID + hh] =
            acc[k];
}

// ---------------- K1b: exclusive running product -> P = u0 = 2^(-(c+a)*log2e) ----
__global__ __launch_bounds__(256) void k_prefix(const float* __restrict__ cvec,
                                                float* __restrict__ CP) {
    int idx = blockIdx.x * 256 + threadIdx.x;   // = b*2048 + h
    int h = idx & (HID - 1);
    float run = exp2f_(-LOG2E * cvec[h]);
    #pragma unroll 4
    for (int s = 0; s < NSEG; ++s) {
        size_t o = (size_t)s * (BATCH * HID) + idx;
        float cs = CP[o];           // read segment product first (aliased buffer)
        CP[o] = run;                // write u0 for this segment
        run *= cs;
    }
}

// ---------------- K2: main scan (no LDS) ----------------
__global__ __launch_bounds__(256) void k_main(const float* __restrict__ Wt,
                                              const float* __restrict__ V,
                                              const unsigned* __restrict__ xb32,
                                              const float* __restrict__ P,
                                              float* __restrict__ WP) {
    const int tid = threadIdx.x, lane = tid & 63, wv = tid >> 6;
    const int hb = blockIdx.x * 256;                 // 8 h-groups
    const int bb = blockIdx.y * 16 + wv * 4;         // 4 b per wave
    const int ib = blockIdx.z * ISEG;                // 32 segments
    const int hh = hb + 4 * lane;
    const bool hi16 = (lane & 16) != 0;
    const bool hi32 = (lane & 32) != 0;

    float4 u[4], s[4];
    #pragma unroll
    for (int k = 0; k < 4; ++k) {
        u[k] = *(const float4*)&P[(size_t)blockIdx.z * (BATCH * HID) +
                                  (size_t)(bb + k) * HID + hh];
        s[k].x = rcpf(1.0f + u[k].x); s[k].y = rcpf(1.0f + u[k].y);
        s[k].z = rcpf(1.0f + u[k].z); s[k].w = rcpf(1.0f + u[k].w);
    }

    for (int tq = 0; tq < 16; ++tq) {                // 16 groups of 8 i-steps
        unsigned sx[4];
        #pragma unroll
        for (int k = 0; k < 4; ++k)
            sx[k] = (unsigned)__builtin_amdgcn_readfirstlane(
                (int)xb32[(bb + k) * 128 + ((ib + tq * 8) >> 5)]);

        float p0[8], p1[8], p2[8], p3[8];
        #pragma unroll
        for (int j = 0; j < 8; ++j) {
            const int ig = ib + tq * 8 + j;
            float4 w4 = *(const float4*)&Wt[(size_t)ig * HID + hh];
            float4 v4 = *(const float4*)&V[(size_t)ig * HID + hh];
            p0[j] = s[0].x * v4.x + s[0].y * v4.y + s[0].z * v4.z + s[0].w * v4.w;
            p1[j] = s[1].x * v4.x + s[1].y * v4.y + s[1].z * v4.z + s[1].w * v4.w;
            p2[j] = s[2].x * v4.x + s[2].y * v4.y + s[2].z * v4.z + s[2].w * v4.w;
            p3[j] = s[3].x * v4.x + s[3].y * v4.y + s[3].z * v4.z + s[3].w * v4.w;
            const int sh = ((tq & 3) * 8) + j;
            if ((sx[0] >> sh) & 1u) {
                u[0].x *= w4.x; u[0].y *= w4.y; u[0].z *= w4.z; u[0].w *= w4.w;
                s[0].x = rcpf(1.0f + u[0].x); s[0].y = rcpf(1.0f + u[0].y);
                s[0].z = rcpf(1.0f + u[0].z); s[0].w = rcpf(1.0f + u[0].w);
            }
            if ((sx[1] >> sh) & 1u) {
                u[1].x *= w4.x; u[1].y *= w4.y; u[1].z *= w4.z; u[1].w *= w4.w;
                s[1].x = rcpf(1.0f + u[1].x); s[1].y = rcpf(1.0f + u[1].y);
                s[1].z = rcpf(1.0f + u[1].z); s[1].w = rcpf(1.0f + u[1].w);
            }
            if ((sx[2] >> sh) & 1u) {
                u[2].x *= w4.x; u[2].y *= w4.y; u[2].z *= w4.z; u[2].w *= w4.w;
                s[2].x = rcpf(1.0f + u[2].x); s[2].y = rcpf(1.0f + u[2].y);
                s[2].z = rcpf(1.0f + u[2].z); s[2].w = rcpf(1.0f + u[2].w);
            }
            if ((sx[3] >> sh) & 1u) {
                u[3].x *= w4.x; u[3].y *= w4.y; u[3].z *= w4.z; u[3].w *= w4.w;
                s[3].x = rcpf(1.0f + u[3].x); s[3].y = rcpf(1.0f + u[3].y);
                s[3].z = rcpf(1.0f + u[3].z); s[3].w = rcpf(1.0f + u[3].w);
            }
        }

        float z[8];
        #pragma unroll
        for (int j = 0; j < 8; ++j) {
            float a01k = hi16 ? p1[j] : p0[j];
            float a01s = hi16 ? p0[j] : p1[j];
            float y01 = a01k + __shfl_xor(a01s, 16);
            float a23k = hi16 ? p3[j] : p2[j];
            float a23s = hi16 ? p2[j] : p3[j];
            float y23 = a23k + __shfl_xor(a23s, 16);
            float bk_ = hi32 ? y23 : y01;
            float bs_ = hi32 ? y01 : y23;
            float zz = bk_ + __shfl_xor(bs_, 32);
            zz = ror_add<0x128>(zz);
            zz = ror_add<0x124>(zz);
            zz = ror_add<0x122>(zz);
            zz = ror_add<0x121>(zz);
            z[j] = zz;
        }
        if ((lane & 15) == 0) {
            const size_t row =
                (size_t)(blockIdx.x * BATCH + bb + (lane >> 4)) * NN + ib + tq * 8;
            *(float4*)&WP[row] = make_float4(z[0], z[1], z[2], z[3]);
            *(float4*)&WP[row + 4] = make_float4(z[4], z[5], z[6], z[7]);
        }
    }
}

// ---------------- K3: finalize ----------------
__global__ __launch_bounds__(256) void k_final(const float* __restrict__ WP,
                                               const float* __restrict__ x,
                                               const float* __restrict__ bv,
                                               float* __restrict__ out) {
    const int b = blockIdx.x, tid = threadIdx.x;
    float acc = 0.f;
    for (int i = tid; i < NN; i += 256) {
        float l = bv[i];
        #pragma unroll
        for (int j = 0; j < 8; ++j)
            l += WP[((size_t)(j * BATCH + b)) * NN + i];
        float xi = x[(size_t)b * NN + i];
        float al = fabsf(l);
        float e = exp2f_(-al * LOG2E);
        float lp = __logf(1.0f + e);
        acc += fminf(l, 0.0f) - lp - (1.0f - xi) * l;
    }
    __shared__ float red[256];
    red[tid] = acc;
    __syncthreads();
    for (int sft = 128; sft > 0; sft >>= 1) {
        if (tid < sft) red[tid] += red[tid + sft];
        __syncthreads();
    }
    if (tid == 0) out[b] = red[0];
}

extern "C" void kernel_launch(void* const* d_in, const int* in_sizes, int n_in,
                              void* d_out, int out_size, void* d_ws, size_t ws_size,
                              hipStream_t stream) {
    const float* x  = (const float*)d_in[0];
    const float* W  = (const float*)d_in[1];
    const float* c  = (const float*)d_in[2];
    const float* V  = (const float*)d_in[3];
    const float* bv = (const float*)d_in[4];
    float* out = (float*)d_out;

    char* ws = (char*)d_ws;
    unsigned long long* xbits = (unsigned long long*)ws;              // 32 KB (pad 64K)
    float* CP = (float*)(ws + (1 << 16));                             // 16 MB
    float* WP = (float*)(ws + (1 << 16) + (size_t)NSEG * BATCH * HID * 4);   // 8 MB
    float* Wt = (float*)(ws + (1 << 16) + (size_t)NSEG * BATCH * HID * 4
                         + (size_t)8 * BATCH * NN * 4);               // 32 MB

    k_pack<<<dim3(1024), dim3(256), 0, stream>>>(x, xbits);
    k_wt<<<dim3(NN / 64, HID / 64), dim3(256), 0, stream>>>(W, Wt);
    k_partial<<<dim3(8, NSEG, 4), dim3(256), 0, stream>>>(Wt, (const unsigned*)xbits, CP);
    k_prefix<<<dim3(512), dim3(256), 0, stream>>>(c, CP);
    k_main<<<dim3(8, 4, NSEG), dim3(256), 0, stream>>>(Wt, V, (const unsigned*)xbits, CP, WP);
    k_final<<<dim3(64), dim3(256), 0, stream>>>(WP, x, bv, out);
}

// Round 4
// 188.628 us; speedup vs baseline: 1.2891x; 1.2891x over previous
//
#include <hip/hip_runtime.h>
#include <hip/hip_bf16.h>
#include <stdint.h>

#define NN 4096
#define HID 2048
#define BATCH 64
#define NSEG 32
#define ISEG 128          // 4096/32
#define LOG2E 1.4426950408889634f

__device__ __forceinline__ float rcpf(float v) { return __builtin_amdgcn_rcpf(v); }
__device__ __forceinline__ float exp2f_(float v) { return __builtin_amdgcn_exp2f(v); }

template <int CTRL>
__device__ __forceinline__ float ror_add(float x) {
    int t = __builtin_amdgcn_update_dpp(0, __builtin_bit_cast(int, x), CTRL, 0xF, 0xF, true);
    return x + __builtin_bit_cast(float, t);
}
__device__ __forceinline__ uint32_t bf16r(float f) {   // round-to-nearest-even top16
    uint32_t b = __builtin_bit_cast(uint32_t, f);
    return (b + 0x7fffu + ((b >> 16) & 1u)) >> 16;
}
__device__ __forceinline__ float hi_f(uint32_t dw) {   // bf16 in high 16 -> f32
    return __builtin_bit_cast(float, dw & 0xffff0000u);
}
__device__ __forceinline__ float lo_f(uint32_t dw) {   // bf16 in low 16 -> f32
    return __builtin_bit_cast(float, dw << 16);
}

// ---------------- K0: pack x bits ----------------
__global__ __launch_bounds__(256) void k_pack(const float* __restrict__ x,
                                              unsigned long long* __restrict__ xbits) {
    int gw = blockIdx.x * 4 + (threadIdx.x >> 6);
    int lane = threadIdx.x & 63;
    int b = gw >> 6, w = gw & 63;
    float v = x[(size_t)b * NN + w * 64 + lane];
    unsigned long long m = __ballot(v > 0.5f);
    if (lane == 0) xbits[b * 64 + w] = m;
}

// ---------------- K_wt: build IV[i][h] = (bf16(V) << 16) | bf16(2^(-w*log2e)-1) ----
__global__ __launch_bounds__(256) void k_wt(const float* __restrict__ W,
                                            const float* __restrict__ V,
                                            uint32_t* __restrict__ IV) {
    __shared__ float lt[64 * 68];
    const int t = threadIdx.x;
    const int i0 = blockIdx.x * 64, h0 = blockIdx.y * 64;
    const int c4 = (t & 15) * 4, rb = t >> 4;
    #pragma unroll
    for (int rr = 0; rr < 4; ++rr) {
        int row = rr * 16 + rb;   // h-row
        float4 w4 = *(const float4*)&W[(size_t)(h0 + row) * NN + i0 + c4];
        *(float4*)&lt[row * 68 + c4] = w4;
    }
    __syncthreads();
    #pragma unroll
    for (int rr = 0; rr < 4; ++rr) {
        int ir = rr * 16 + rb;    // i-row
        float4 vv = *(const float4*)&V[(size_t)(i0 + ir) * HID + h0 + c4];
        uint4 o;
        o.x = (bf16r(vv.x) << 16) | bf16r(exp2f_(-LOG2E * lt[(c4 + 0) * 68 + ir]) - 1.0f);
        o.y = (bf16r(vv.y) << 16) | bf16r(exp2f_(-LOG2E * lt[(c4 + 1) * 68 + ir]) - 1.0f);
        o.z = (bf16r(vv.z) << 16) | bf16r(exp2f_(-LOG2E * lt[(c4 + 2) * 68 + ir]) - 1.0f);
        o.w = (bf16r(vv.w) << 16) | bf16r(exp2f_(-LOG2E * lt[(c4 + 3) * 68 + ir]) - 1.0f);
        *(uint4*)&IV[(size_t)(i0 + ir) * HID + h0 + c4] = o;
    }
}

// ---------------- K1: per-segment products C[seg][b][h] = prod (1+d) ----------------
__global__ __launch_bounds__(256) void k_partial(const uint32_t* __restrict__ IV,
                                                 const unsigned long long* __restrict__ xb,
                                                 float* __restrict__ C) {
    const int tid = threadIdx.x, lane = tid & 63, wv = tid >> 6;
    const int hb = blockIdx.x * 256, ib = blockIdx.y * ISEG;
    const int bb = blockIdx.z * 32 + wv * 8;
    const int hh = hb + 4 * lane;

    float4 acc[8];
    #pragma unroll
    for (int k = 0; k < 8; ++k) acc[k] = make_float4(1.f, 1.f, 1.f, 1.f);

    unsigned long long xw[8][2];
    #pragma unroll
    for (int k = 0; k < 8; ++k) {
        #pragma unroll
        for (int hf = 0; hf < 2; ++hf) {
            unsigned long long tt = xb[(bb + k) * 64 + (ib >> 6) + hf];
            uint32_t lo = __builtin_amdgcn_readfirstlane((uint32_t)tt);
            uint32_t hi = __builtin_amdgcn_readfirstlane((uint32_t)(tt >> 32));
            xw[k][hf] = ((unsigned long long)hi << 32) | lo;
        }
    }

    uint32_t off = (uint32_t)(((size_t)ib * HID + hh) * 4u);
    #pragma unroll
    for (int hf = 0; hf < 2; ++hf) {
        for (int tq = 0; tq < 16; ++tq) {
            #pragma unroll
            for (int j = 0; j < 4; ++j) {
                uint4 q = *(const uint4*)((const char*)IV + off);
                off += HID * 4;
                float d0 = lo_f(q.x), d1 = lo_f(q.y), d2 = lo_f(q.z), d3 = lo_f(q.w);
                int sh = tq * 4 + j;
                #pragma unroll
                for (int k = 0; k < 8; ++k) {
                    if ((xw[k][hf] >> sh) & 1ull) {
                        acc[k].x += acc[k].x * d0; acc[k].y += acc[k].y * d1;
                        acc[k].z += acc[k].z * d2; acc[k].w += acc[k].w * d3;
                    }
                }
            }
        }
    }
    #pragma unroll
    for (int k = 0; k < 8; ++k)
        *(float4*)&C[(size_t)blockIdx.y * (BATCH * HID) + (size_t)(bb + k) * HID + hh] =
            acc[k];
}

// ---------------- K1b: exclusive running product -> P = u0 per segment ----------------
__global__ __launch_bounds__(256) void k_prefix(const float* __restrict__ cvec,
                                                float* __restrict__ CP) {
    int idx = blockIdx.x * 256 + threadIdx.x;   // = b*2048 + h
    int h = idx & (HID - 1);
    float run = exp2f_(-LOG2E * cvec[h]);
    #pragma unroll 4
    for (int s = 0; s < NSEG; ++s) {
        size_t o = (size_t)s * (BATCH * HID) + idx;
        float cs = CP[o];
        CP[o] = run;
        run *= cs;
    }
}

// ---------------- K2: main scan ----------------
__global__ __launch_bounds__(256, 4) void k_main(const uint32_t* __restrict__ IV,
                                                 const unsigned long long* __restrict__ xb,
                                                 const float* __restrict__ P,
                                                 float* __restrict__ WP) {
    const int tid = threadIdx.x, lane = tid & 63, wv = tid >> 6;
    const int hb = blockIdx.x * 256;                 // 8 h-groups (-> XCD = x%8)
    const int bb = blockIdx.y * 16 + wv * 4;         // 4 b per wave
    const int ib = blockIdx.z * ISEG;                // 32 segments
    const int hh = hb + 4 * lane;
    const bool hi16 = (lane & 16) != 0;
    const bool hi32 = (lane & 32) != 0;

    float4 u[4], s[4];
    #pragma unroll
    for (int k = 0; k < 4; ++k) {
        u[k] = *(const float4*)&P[(size_t)blockIdx.z * (BATCH * HID) +
                                  (size_t)(bb + k) * HID + hh];
        s[k].x = rcpf(1.f + u[k].x); s[k].y = rcpf(1.f + u[k].y);
        s[k].z = rcpf(1.f + u[k].z); s[k].w = rcpf(1.f + u[k].w);
    }

    unsigned long long xw[4][2];
    #pragma unroll
    for (int k = 0; k < 4; ++k) {
        #pragma unroll
        for (int hf = 0; hf < 2; ++hf) {
            unsigned long long tt = xb[(bb + k) * 64 + (ib >> 6) + hf];
            uint32_t lo = __builtin_amdgcn_readfirstlane((uint32_t)tt);
            uint32_t hi = __builtin_amdgcn_readfirstlane((uint32_t)(tt >> 32));
            xw[k][hf] = ((unsigned long long)hi << 32) | lo;
        }
    }

    uint32_t off = (uint32_t)(((size_t)ib * HID + hh) * 4u);
    uint4 q0 = *(const uint4*)((const char*)IV + off);
    uint4 q1 = *(const uint4*)((const char*)IV + off + HID * 4);
    uint4 q2 = *(const uint4*)((const char*)IV + off + HID * 8);
    uint4 q3 = *(const uint4*)((const char*)IV + off + HID * 12);
    off += HID * 16;

    #pragma unroll
    for (int hf = 0; hf < 2; ++hf) {
        for (int tq = 0; tq < 16; ++tq) {
            uint4 c0 = q0, c1 = q1, c2 = q2, c3 = q3;
            if (!(hf == 1 && tq == 15)) {
                q0 = *(const uint4*)((const char*)IV + off);
                q1 = *(const uint4*)((const char*)IV + off + HID * 4);
                q2 = *(const uint4*)((const char*)IV + off + HID * 8);
                q3 = *(const uint4*)((const char*)IV + off + HID * 12);
                off += HID * 16;
            }
            float z[4];
            #pragma unroll
            for (int j = 0; j < 4; ++j) {
                uint4 cq = (j == 0) ? c0 : (j == 1) ? c1 : (j == 2) ? c2 : c3;
                float v0 = hi_f(cq.x), v1 = hi_f(cq.y), v2 = hi_f(cq.z), v3 = hi_f(cq.w);
                float p0 = s[0].x * v0 + s[0].y * v1 + s[0].z * v2 + s[0].w * v3;
                float p1 = s[1].x * v0 + s[1].y * v1 + s[1].z * v2 + s[1].w * v3;
                float p2 = s[2].x * v0 + s[2].y * v1 + s[2].z * v2 + s[2].w * v3;
                float p3 = s[3].x * v0 + s[3].y * v1 + s[3].z * v2 + s[3].w * v3;
                const int sh = tq * 4 + j;
                float d0 = lo_f(cq.x), d1 = lo_f(cq.y), d2 = lo_f(cq.z), d3 = lo_f(cq.w);
                #pragma unroll
                for (int k = 0; k < 4; ++k) {
                    if ((xw[k][hf] >> sh) & 1ull) {
                        u[k].x += u[k].x * d0; u[k].y += u[k].y * d1;
                        u[k].z += u[k].z * d2; u[k].w += u[k].w * d3;
                        s[k].x = rcpf(1.f + u[k].x); s[k].y = rcpf(1.f + u[k].y);
                        s[k].z = rcpf(1.f + u[k].z); s[k].w = rcpf(1.f + u[k].w);
                    }
                }
                float a01k = hi16 ? p1 : p0;
                float a01s = hi16 ? p0 : p1;
                float y01 = a01k + __shfl_xor(a01s, 16);
                float a23k = hi16 ? p3 : p2;
                float a23s = hi16 ? p2 : p3;
                float y23 = a23k + __shfl_xor(a23s, 16);
                float bk_ = hi32 ? y23 : y01;
                float bs_ = hi32 ? y01 : y23;
                float zz = bk_ + __shfl_xor(bs_, 32);
                zz = ror_add<0x128>(zz);
                zz = ror_add<0x124>(zz);
                zz = ror_add<0x122>(zz);
                zz = ror_add<0x121>(zz);
                z[j] = zz;
            }
            if ((lane & 15) == 0) {
                *(float4*)&WP[(size_t)(blockIdx.x * BATCH + bb + (lane >> 4)) * NN +
                              ib + hf * 64 + tq * 4] = make_float4(z[0], z[1], z[2], z[3]);
            }
        }
    }
}

// ---------------- K3: finalize ----------------
__global__ __launch_bounds__(256) void k_final(const float* __restrict__ WP,
                                               const float* __restrict__ x,
                                               const float* __restrict__ bv,
                                               float* __restrict__ out) {
    const int b = blockIdx.x, tid = threadIdx.x;
    float acc = 0.f;
    for (int i = tid; i < NN; i += 256) {
        float l = bv[i];
        #pragma unroll
        for (int j = 0; j < 8; ++j)
            l += WP[((size_t)(j * BATCH + b)) * NN + i];
        float xi = x[(size_t)b * NN + i];
        float al = fabsf(l);
        float e = exp2f_(-al * LOG2E);
        float lp = __logf(1.0f + e);
        acc += fminf(l, 0.0f) - lp - (1.0f - xi) * l;
    }
    __shared__ float red[256];
    red[tid] = acc;
    __syncthreads();
    for (int sft = 128; sft > 0; sft >>= 1) {
        if (tid < sft) red[tid] += red[tid + sft];
        __syncthreads();
    }
    if (tid == 0) out[b] = red[0];
}

extern "C" void kernel_launch(void* const* d_in, const int* in_sizes, int n_in,
                              void* d_out, int out_size, void* d_ws, size_t ws_size,
                              hipStream_t stream) {
    const float* x  = (const float*)d_in[0];
    const float* W  = (const float*)d_in[1];
    const float* c  = (const float*)d_in[2];
    const float* V  = (const float*)d_in[3];
    const float* bv = (const float*)d_in[4];
    float* out = (float*)d_out;

    char* ws = (char*)d_ws;
    unsigned long long* xbits = (unsigned long long*)ws;               // 32 KB (pad 64K)
    float* CP = (float*)(ws + (1 << 16));                              // 16 MB
    float* WP = (float*)(ws + (1 << 16) + (size_t)NSEG * BATCH * HID * 4);  // 8 MB
    uint32_t* IV = (uint32_t*)(ws + (1 << 16) + (size_t)NSEG * BATCH * HID * 4
                               + (size_t)8 * BATCH * NN * 4);          // 32 MB

    k_pack<<<dim3(1024), dim3(256), 0, stream>>>(x, xbits);
    k_wt<<<dim3(NN / 64, HID / 64), dim3(256), 0, stream>>>(W, V, IV);
    k_partial<<<dim3(8, NSEG, 2), dim3(256), 0, stream>>>(IV, xbits, CP);
    k_prefix<<<dim3(512), dim3(256), 0, stream>>>(c, CP);
    k_main<<<dim3(8, 4, NSEG), dim3(256), 0, stream>>>(IV, xbits, CP, WP);
    k_final<<<dim3(64), dim3(256), 0, stream>>>(WP, x, bv, out);
}